// Round 8
// baseline (315.411 us; speedup 1.0000x reference)
//
#include <hip/hip_runtime.h>
#include <math.h>

#define NEGINF (-INFINITY)
#define NEGINF_BITS ((int)0xFF800000)

typedef unsigned int u32;
typedef unsigned long long u64;

#define RST 64   // rows staged in STATIC LDS (64 rows x 256 f32 = 64 KiB).
                 // Static __shared__ cannot silently fall back like the
                 // >64KiB dynamic path did in R5/R7 (bank-conflict ctr -> 0).

__device__ __forceinline__ int rl_i(int x, int l) {
    return __builtin_amdgcn_readlane(x, l);
}
__device__ __forceinline__ float rl_f(float x, int l) {
    return __int_as_float(__builtin_amdgcn_readlane(__float_as_int(x), l));
}

// One DPP max stage: x = max(x, lanes-moved(x)). bound_ctrl=false + old=x makes
// invalid source lanes contribute x itself (identity for max).
template <int CTRL>
__device__ __forceinline__ float dppmax(float x) {
    int xi = __float_as_int(x);
    int yi = __builtin_amdgcn_update_dpp(xi, xi, CTRL, 0xf, 0xf, false);
    return fmaxf(x, __int_as_float(yi));
}

// Wave64 max via DPP: row_shr 1/2/4/8 then row_bcast 15/31, broadcast from
// lane 63. Value-only chain = minimum latency (R6: carrying the index through
// the chain costs ~2x).
__device__ __forceinline__ float wave_max64(float x) {
    x = dppmax<0x111>(x);   // row_shr:1
    x = dppmax<0x112>(x);   // row_shr:2
    x = dppmax<0x114>(x);   // row_shr:4
    x = dppmax<0x118>(x);   // row_shr:8
    x = dppmax<0x142>(x);   // row_bcast:15
    x = dppmax<0x143>(x);   // row_bcast:31
    return rl_f(x, 63);
}

// Wave argmax over (v, idx), tie-break lowest idx (matches jnp.argmax
// first-occurrence). Fast path: single lane holds the max -> one readlane.
__device__ __forceinline__ void wave_argmax(float v, int idx, float& out_v, int& out_idx) {
    float mv = wave_max64(v);
    u64 mask = __ballot(v == mv);
    int ln = (int)__builtin_ctzll(mask);
    int bi = rl_i(idx, ln);
    u64 rest = mask & (mask - 1);
    if (rest) {                       // wave-uniform, almost never taken
        while (rest) {
            int l2 = (int)__builtin_ctzll(rest); rest &= rest - 1;
            int b2 = rl_i(idx, l2);
            if (b2 < bi) bi = b2;
        }
    }
    out_v = mv; out_idx = bi;
}

// Joint top-2 wave reduction over a SINGLE ROW's 256 values (rescan path),
// given lane-local top-2 (lv,lf) >= (lv2,lf2), first-occurrence ordering.
// One 6-stage DPP chain carries (top, second); DPP old = NEGINF injects the
// neutral element for invalid source lanes. (Verified R3-R7, absmax=0.)
__device__ __forceinline__ void wave_top2(float lv, int lf, float lv2, int lf2,
                                          float& nv, int& nc, float& nv2, int& nc2) {
    float av = lv, bv = lv2;
#define T2STAGE(CTRL) {                                                        \
        float a2 = __int_as_float(__builtin_amdgcn_update_dpp(                 \
            NEGINF_BITS, __float_as_int(av), CTRL, 0xf, 0xf, false));          \
        float b2 = __int_as_float(__builtin_amdgcn_update_dpp(                 \
            NEGINF_BITS, __float_as_int(bv), CTRL, 0xf, 0xf, false));          \
        float t = fminf(av, a2);                                               \
        av = fmaxf(av, a2);                                                    \
        bv = fmaxf(fmaxf(bv, b2), t); }
    T2STAGE(0x111) T2STAGE(0x112) T2STAGE(0x114) T2STAGE(0x118)
    T2STAGE(0x142) T2STAGE(0x143)
#undef T2STAGE
    nv = rl_f(av, 63);
    float sv = rl_f(bv, 63);

    u64 m1 = __ballot(lv == nv);
    int ln = (int)__builtin_ctzll(m1);
    nc = rl_i(lf, ln);

    nv2 = sv; nc2 = 300;
    if (sv > 0.f) {
        if (sv == nv) {
            // duplicate max: candidates are lane ln's lf2 (if lv2==nv) or the
            // next lane in m1 (lowest-col-first within/across lanes).
            float b2v = rl_f(lv2, ln);
            if (b2v == nv) {
                nc2 = rl_i(lf2, ln);
            } else {
                u64 rest = m1 & (m1 - 1);
                int l2 = (int)__builtin_ctzll(rest);
                nc2 = rl_i(lf, l2);
            }
        } else {
            u64 m2 = __ballot(lv == sv || lv2 == sv);
            int l2 = (int)__builtin_ctzll(m2);
            float tl = rl_f(lv, l2);
            nc2 = (tl == sv) ? rl_i(lf, l2) : rl_i(lf2, l2);
        }
    }
}

// One wave (64 lanes) per batch. Lane l owns rows {j*64+l : j=0..3}:
//   rv[j]/rc[j]  : row's exact best (value, col) over untaken cols; rc==300 = DEAD.
//   spv[j]/spc[j]: row's exact runner-up (spare), eagerly invalidated when its
//                  col is taken; spc==300 = none.
//   acol[j]      : col assigned to this row (recorded at kill; every row is
//                  killed exactly once). Ones stored AFTER the loop.
// Lane l owns taken-bits for cols 4l..4l+3 (colmask).
// Rows 0..RST-1 (the j=0 rows) are staged in static LDS at init (chunk-XOR
// swizzle, verified); their rescans read ~150cy LDS instead of L2/HBM.
__global__ __launch_bounds__(64, 1) void greedy_perm_kernel(
        const float* __restrict__ soft, float* __restrict__ out) {
    __shared__ float smem[RST * 256];             // 64 KiB static
    const int b = blockIdx.x;
    const int lane = threadIdx.x;
    const size_t base = (size_t)b << 16;          // b * 256 * 256
    const float* sc = soft + base;
    float* ob = out + base;

    float rv[4], spv[4];
    int   rc[4], spc[4], acol[4];
#pragma unroll
    for (int j = 0; j < 4; ++j) {
        rv[j] = NEGINF; rc[j] = 0; spv[j] = NEGINF; spc[j] = 300; acol[j] = 0;
    }

    const float4 zero4 = make_float4(0.f, 0.f, 0.f, 0.f);

    // ---- initial per-row top-2 scan, 16 loads in flight, fused zero-fill of
    // ---- out, fused LDS staging of rows 0..RST-1 (lane l stages row l) ----
    for (int k = 0; k < 64; k += 4) {
        float4 w[4][4];
#pragma unroll
        for (int j = 0; j < 4; ++j) {
            const float4* rp = (const float4*)(sc + (size_t)(j * 64 + lane) * 256);
#pragma unroll
            for (int kk = 0; kk < 4; ++kk) w[j][kk] = rp[k + kk];
        }
#pragma unroll
        for (int j = 0; j < 4; ++j) {
            float4* op = (float4*)(ob + (size_t)(j * 64 + lane) * 256);
#pragma unroll
            for (int kk = 0; kk < 4; ++kk) op[k + kk] = zero4;
        }
        {
            // row `lane` (j=0): store chunk c at slot c^lane -> 64 lanes' 16B
            // writes spread across bank groups (verified swizzle, R3/R4).
            float* lp = &smem[lane << 8];
#pragma unroll
            for (int kk = 0; kk < 4; ++kk)
                *(float4*)&lp[((k + kk) ^ lane) << 2] = w[0][kk];
        }
#pragma unroll
        for (int j = 0; j < 4; ++j) {
#pragma unroll
            for (int kk = 0; kk < 4; ++kk) {
                const float4 ww = w[j][kk];
                const int bc = 4 * (k + kk);
                const float e[4] = {ww.x, ww.y, ww.z, ww.w};
#pragma unroll
                for (int q = 0; q < 4; ++q) {
                    const float x = e[q];
                    const int   cx = bc + q;
                    const bool g1 = x > rv[j];
                    const bool g2 = x > spv[j];
                    spv[j] = g1 ? rv[j] : (g2 ? x  : spv[j]);
                    spc[j] = g1 ? rc[j] : (g2 ? cx : spc[j]);
                    rv[j]  = g1 ? x  : rv[j];
                    rc[j]  = g1 ? cx : rc[j];
                }
            }
        }
    }

    // Zero-stores drain before the final 1.0 stores (same-lane, same rows;
    // fence is belt-and-braces and cheap, outside the step loop).
    __threadfence_block();

    u32 colmask = 0;   // 4 bits: cols 4*lane..4*lane+3 assigned?

    // ---- 256 sequential greedy steps ----
    for (int step = 0; step < 256; ++step) {
        // local merge over the lane's 4 rows, j ascending => flat ascending,
        // strict > keeps first occurrence.
        float bv = rv[0];
        int   bf = (lane << 8) | (rc[0] & 255);
#pragma unroll
        for (int j = 1; j < 4; ++j) {
            if (rv[j] > bv) { bv = rv[j]; bf = (((j * 64 + lane)) << 8) | (rc[j] & 255); }
        }
        float gv; int gf;
        wave_argmax(bv, bf, gv, gf);
        (void)gv;
        const int r  = gf >> 8;
        const int cc = gf & 255;

        if (lane == (cc >> 2)) colmask |= 1u << (cc & 3);
        const bool iown = (lane == (r & 63));
        const int  rj   = r >> 6;

        // fused pass: spare invalidation, winner kill (+assignment record),
        // dirty advance, rescan mark. Winner row has rc[rj]==cc by construction.
        u32 needmask = 0;
#pragma unroll
        for (int j = 0; j < 4; ++j) {
            if (spc[j] == cc) spc[j] = 300;        // eager spare invalidation
            if (rc[j] == cc) {                     // dead rows: rc==300, never
                if (iown && j == rj) {             // winner: kill + record col
                    rv[j] = NEGINF; rc[j] = 300; acol[j] = cc;
                } else if (spc[j] < 300) {         // exact in-register advance
                    rv[j] = spv[j]; rc[j] = spc[j];
                    spv[j] = NEGINF; spc[j] = 300;
                } else {
                    needmask |= 1u << j;
                }
            }
        }

        u64 nb = __ballot(needmask != 0);          // the step's ONLY ballot
        while (nb) {                               // rare (~25% of steps)
            const int l = (int)__builtin_ctzll(nb); nb &= nb - 1;
            u32 nm = (u32)rl_i((int)needmask, l);
            while (nm) {
                const int j = (int)__builtin_ctzll(nm); nm &= nm - 1;
                const int row = (j << 6) + l;
                // coalesced: 64 lanes x float4 = the whole 256-float row.
                // Rows < RST live in LDS (j=0 rows; owner lane == row).
                float4 w = (row < RST)
                    ? *(const float4*)&smem[(row << 8) | (((lane ^ l) & 63) << 2)]
                    : *(const float4*)(sc + ((size_t)row << 8) + (lane << 2));
                const float q0 = (colmask & 1u) ? NEGINF : w.x;
                const float q1 = (colmask & 2u) ? NEGINF : w.y;
                const float q2 = (colmask & 4u) ? NEGINF : w.z;
                const float q3 = (colmask & 8u) ? NEGINF : w.w;
                const int cb = lane << 2;
                float lv = q0; int lf = cb;
                float lv2 = NEGINF; int lf2 = cb;
                {
                    bool g1 = q1 > lv, g2 = q1 > lv2;
                    lv2 = g1 ? lv : (g2 ? q1 : lv2); lf2 = g1 ? lf : (g2 ? cb + 1 : lf2);
                    lv  = g1 ? q1 : lv;              lf  = g1 ? cb + 1 : lf;
                    g1 = q2 > lv; g2 = q2 > lv2;
                    lv2 = g1 ? lv : (g2 ? q2 : lv2); lf2 = g1 ? lf : (g2 ? cb + 2 : lf2);
                    lv  = g1 ? q2 : lv;              lf  = g1 ? cb + 2 : lf;
                    g1 = q3 > lv; g2 = q3 > lv2;
                    lv2 = g1 ? lv : (g2 ? q3 : lv2); lf2 = g1 ? lf : (g2 ? cb + 3 : lf2);
                    lv  = g1 ? q3 : lv;              lf  = g1 ? cb + 3 : lf;
                }
                float fv, fv2; int fc, fc2;
                wave_top2(lv, lf, lv2, lf2, fv, fc, fv2, fc2);
                if (lane == l) {
#pragma unroll
                    for (int jj = 0; jj < 4; ++jj) if (jj == j) {
                        rv[jj] = fv; rc[jj] = fc;
                        spv[jj] = fv2; spc[jj] = fc2;   // fc2==300 if none
                    }
                }
            }
        }
    }

    // ---- deferred one-stores: 4 per lane, each to a row this lane zero-filled
    // ---- (same-lane program order => the 1.0 lands after the zeros) ----
#pragma unroll
    for (int j = 0; j < 4; ++j)
        ob[(size_t)(j * 64 + lane) * 256 + acol[j]] = 1.0f;
}

extern "C" void kernel_launch(void* const* d_in, const int* in_sizes, int n_in,
                              void* d_out, int out_size, void* d_ws, size_t ws_size,
                              hipStream_t stream) {
    const float* soft = (const float*)d_in[0];
    float* out = (float*)d_out;
    const int n_batches = in_sizes[0] >> 16;   // elements / (256*256)

    // Static 64 KiB LDS: no runtime attribute, no silent fallback.
    greedy_perm_kernel<<<n_batches, 64, 0, stream>>>(soft, out);
}

// Round 9
// 300.868 us; speedup vs baseline: 1.0483x; 1.0483x over previous
//
#include <hip/hip_runtime.h>
#include <math.h>

#define NEGINF (-INFINITY)
#define NEGINF_BITS ((int)0xFF800000)

typedef unsigned int u32;
typedef unsigned long long u64;

#define RST 64   // rows staged in STATIC LDS (64 rows x 256 f32 = 64 KiB).
                 // Static __shared__ cannot silently fall back the way the
                 // >64KiB dynamic opt-in did in R5/R7 (bank-conflict ctr -> 0,
                 // FETCH up). R8 verified this staging path (absmax=0).

__device__ __forceinline__ int rl_i(int x, int l) {
    return __builtin_amdgcn_readlane(x, l);
}
__device__ __forceinline__ float rl_f(float x, int l) {
    return __int_as_float(__builtin_amdgcn_readlane(__float_as_int(x), l));
}

// One DPP max stage: x = max(x, lanes-moved(x)). bound_ctrl=false + old=x makes
// invalid source lanes contribute x itself (identity for max).
template <int CTRL>
__device__ __forceinline__ float dppmax(float x) {
    int xi = __float_as_int(x);
    int yi = __builtin_amdgcn_update_dpp(xi, xi, CTRL, 0xf, 0xf, false);
    return fmaxf(x, __int_as_float(yi));
}

// Wave64 max via DPP: row_shr 1/2/4/8 then row_bcast 15/31, broadcast from
// lane 63. Value-only chain = minimum latency (R6: carrying the index through
// the chain costs ~2x).
__device__ __forceinline__ float wave_max64(float x) {
    x = dppmax<0x111>(x);   // row_shr:1
    x = dppmax<0x112>(x);   // row_shr:2
    x = dppmax<0x114>(x);   // row_shr:4
    x = dppmax<0x118>(x);   // row_shr:8
    x = dppmax<0x142>(x);   // row_bcast:15
    x = dppmax<0x143>(x);   // row_bcast:31
    return rl_f(x, 63);
}

// Wave argmax over (v, idx), tie-break lowest idx (matches jnp.argmax
// first-occurrence). Fast path: single lane holds the max -> one readlane.
__device__ __forceinline__ void wave_argmax(float v, int idx, float& out_v, int& out_idx) {
    float mv = wave_max64(v);
    u64 mask = __ballot(v == mv);
    int ln = (int)__builtin_ctzll(mask);
    int bi = rl_i(idx, ln);
    u64 rest = mask & (mask - 1);
    if (rest) {                       // wave-uniform, almost never taken
        while (rest) {
            int l2 = (int)__builtin_ctzll(rest); rest &= rest - 1;
            int b2 = rl_i(idx, l2);
            if (b2 < bi) bi = b2;
        }
    }
    out_v = mv; out_idx = bi;
}

// Joint top-2 wave reduction over a SINGLE ROW's 256 values (rescan path),
// given lane-local top-2 (lv,lf) >= (lv2,lf2), first-occurrence ordering.
// One 6-stage DPP chain carries (top, second); DPP old = NEGINF injects the
// neutral element for invalid source lanes. (Verified R3-R8, absmax=0.)
__device__ __forceinline__ void wave_top2(float lv, int lf, float lv2, int lf2,
                                          float& nv, int& nc, float& nv2, int& nc2) {
    float av = lv, bv = lv2;
#define T2STAGE(CTRL) {                                                        \
        float a2 = __int_as_float(__builtin_amdgcn_update_dpp(                 \
            NEGINF_BITS, __float_as_int(av), CTRL, 0xf, 0xf, false));          \
        float b2 = __int_as_float(__builtin_amdgcn_update_dpp(                 \
            NEGINF_BITS, __float_as_int(bv), CTRL, 0xf, 0xf, false));          \
        float t = fminf(av, a2);                                               \
        av = fmaxf(av, a2);                                                    \
        bv = fmaxf(fmaxf(bv, b2), t); }
    T2STAGE(0x111) T2STAGE(0x112) T2STAGE(0x114) T2STAGE(0x118)
    T2STAGE(0x142) T2STAGE(0x143)
#undef T2STAGE
    nv = rl_f(av, 63);
    float sv = rl_f(bv, 63);

    u64 m1 = __ballot(lv == nv);
    int ln = (int)__builtin_ctzll(m1);
    nc = rl_i(lf, ln);

    nv2 = sv; nc2 = 300;
    if (sv > 0.f) {
        if (sv == nv) {
            // duplicate max: candidates are lane ln's lf2 (if lv2==nv) or the
            // next lane in m1 (lowest-col-first within/across lanes).
            float b2v = rl_f(lv2, ln);
            if (b2v == nv) {
                nc2 = rl_i(lf2, ln);
            } else {
                u64 rest = m1 & (m1 - 1);
                int l2 = (int)__builtin_ctzll(rest);
                nc2 = rl_i(lf, l2);
            }
        } else {
            u64 m2 = __ballot(lv == sv || lv2 == sv);
            int l2 = (int)__builtin_ctzll(m2);
            float tl = rl_f(lv, l2);
            nc2 = (tl == sv) ? rl_i(lf, l2) : rl_i(lf2, l2);
        }
    }
}

// One wave (64 lanes) per batch. Lane l owns rows {j*64+l : j=0..3}:
//   rv[j]/rc[j]  : row's exact best (value, col) over untaken cols; rc==300 = DEAD.
//   spv[j]/spc[j]: row's exact runner-up (spare), eagerly invalidated when its
//                  col is taken; spc==300 = none.
// Lane l owns taken-bits for cols 4l..4l+3 (colmask).
// EXACT Round-4 step structure (the 214 us measurement): wave argmax ->
// lane0 store -> winner kill -> spare invalidation -> dd/anyd skip-ballot ->
// per-j {advance | ballot(need) + rescan}. Only the LDS mechanism differs
// (static 64 KiB, rows 0..63, vs dynamic 128 KiB).
__global__ __launch_bounds__(64, 1) void greedy_perm_kernel(
        const float* __restrict__ soft, float* __restrict__ out) {
    __shared__ float smem[RST * 256];             // 64 KiB static
    const int b = blockIdx.x;
    const int lane = threadIdx.x;
    const size_t base = (size_t)b << 16;          // b * 256 * 256
    const float* sc = soft + base;
    float* ob = out + base;

    float rv[4], spv[4];
    int   rc[4], spc[4];
#pragma unroll
    for (int j = 0; j < 4; ++j) { rv[j] = NEGINF; rc[j] = 0; spv[j] = NEGINF; spc[j] = 300; }

    const float4 zero4 = make_float4(0.f, 0.f, 0.f, 0.f);

    // ---- initial per-row top-2 scan, 16 loads in flight, fused zero-fill of
    // ---- out, fused LDS staging of rows 0..RST-1 (lane l stages row l,
    // ---- chunk-XOR swizzled; verified R8) ----
    for (int k = 0; k < 64; k += 4) {
        float4 w[4][4];
#pragma unroll
        for (int j = 0; j < 4; ++j) {
            const float4* rp = (const float4*)(sc + (size_t)(j * 64 + lane) * 256);
#pragma unroll
            for (int kk = 0; kk < 4; ++kk) w[j][kk] = rp[k + kk];
        }
#pragma unroll
        for (int j = 0; j < 4; ++j) {
            float4* op = (float4*)(ob + (size_t)(j * 64 + lane) * 256);
#pragma unroll
            for (int kk = 0; kk < 4; ++kk) op[k + kk] = zero4;
        }
        {
            // row `lane` (j=0): store chunk c at slot c^lane -> 64 lanes' 16B
            // writes spread across bank groups.
            float* lp = &smem[lane << 8];
#pragma unroll
            for (int kk = 0; kk < 4; ++kk)
                *(float4*)&lp[((k + kk) ^ lane) << 2] = w[0][kk];
        }
#pragma unroll
        for (int j = 0; j < 4; ++j) {
#pragma unroll
            for (int kk = 0; kk < 4; ++kk) {
                const float4 ww = w[j][kk];
                const int bc = 4 * (k + kk);
                const float e[4] = {ww.x, ww.y, ww.z, ww.w};
#pragma unroll
                for (int q = 0; q < 4; ++q) {
                    const float x = e[q];
                    const int   cx = bc + q;
                    const bool g1 = x > rv[j];
                    const bool g2 = x > spv[j];
                    spv[j] = g1 ? rv[j] : (g2 ? x  : spv[j]);
                    spc[j] = g1 ? rc[j] : (g2 ? cx : spc[j]);
                    rv[j]  = g1 ? x  : rv[j];
                    rc[j]  = g1 ? cx : rc[j];
                }
            }
        }
    }

    // Drain zero-stores before any 1.0 store can target the same address.
    __threadfence_block();

    u32 colmask = 0;   // 4 bits: cols 4*lane..4*lane+3 assigned?

    // ---- 256 sequential greedy steps (Round-4 structure, verbatim) ----
    for (int step = 0; step < 256; ++step) {
        // A: argmax over cached row bests. Row-ascending iteration makes the
        // flat-index tie-break implicit: strict > only.
        float bv = rv[0];
        int   bf = (lane << 8) | (rc[0] & 255);
#pragma unroll
        for (int j = 1; j < 4; ++j) {
            if (rv[j] > bv) { bv = rv[j]; bf = (((j << 6) + lane) << 8) | (rc[j] & 255); }
        }
        float gv; int gf;
        wave_argmax(bv, bf, gv, gf);
        (void)gv;
        const int r  = gf >> 8;
        const int cc = gf & 255;

        if (lane == 0) ob[gf] = 1.0f;            // hard[r][cc] = 1
        if (lane == (r & 63)) {                  // winner row -> dead
            const int rj = r >> 6;
#pragma unroll
            for (int j = 0; j < 4; ++j) if (j == rj) { rv[j] = NEGINF; rc[j] = 300; }
        }
        if (lane == (cc >> 2)) colmask |= 1u << (cc & 3);

        // spare invalidation: a spare whose col was just taken dies (eager).
#pragma unroll
        for (int j = 0; j < 4; ++j) if (spc[j] == cc) spc[j] = 300;

        // dirty rows (best col just taken): one combined ballot skips the
        // whole section on the ~37% of steps where no row is dirty.
        bool dd[4]; bool anyd = false;
#pragma unroll
        for (int j = 0; j < 4; ++j) { dd[j] = (rc[j] == cc); anyd |= dd[j]; }
        if (__ballot(anyd)) {
#pragma unroll
            for (int j = 0; j < 4; ++j) {
                const bool need = dd[j] && (spc[j] == 300);
                if (dd[j] && !need) {            // exact in-register advance
                    rv[j] = spv[j]; rc[j] = spc[j];
                    spv[j] = NEGINF; spc[j] = 300;
                }
                u64 m = __ballot(need);
                while (m) {
                    const int ln = (int)__builtin_ctzll(m); m &= m - 1;
                    const int row = (j << 6) + ln;
                    // coalesced: 64 lanes x float4 = the whole 256-float row.
                    // Rows < RST live in LDS (j=0 rows; owner lane == row).
                    float4 w = (row < RST)
                        ? *(const float4*)&smem[(row << 8) | (((lane ^ ln) & 63) << 2)]
                        : *(const float4*)(sc + ((size_t)row << 8) + (lane << 2));
                    const float q0 = (colmask & 1u) ? NEGINF : w.x;
                    const float q1 = (colmask & 2u) ? NEGINF : w.y;
                    const float q2 = (colmask & 4u) ? NEGINF : w.z;
                    const float q3 = (colmask & 8u) ? NEGINF : w.w;
                    // lane-local top-2, first-occurrence (strict >)
                    const int cb = lane << 2;
                    float lv = q0; int lf = cb;
                    float lv2 = NEGINF; int lf2 = cb;
                    {
                        bool g1 = q1 > lv, g2 = q1 > lv2;
                        lv2 = g1 ? lv : (g2 ? q1 : lv2); lf2 = g1 ? lf : (g2 ? cb + 1 : lf2);
                        lv  = g1 ? q1 : lv;              lf  = g1 ? cb + 1 : lf;
                        g1 = q2 > lv; g2 = q2 > lv2;
                        lv2 = g1 ? lv : (g2 ? q2 : lv2); lf2 = g1 ? lf : (g2 ? cb + 2 : lf2);
                        lv  = g1 ? q2 : lv;              lf  = g1 ? cb + 2 : lf;
                        g1 = q3 > lv; g2 = q3 > lv2;
                        lv2 = g1 ? lv : (g2 ? q3 : lv2); lf2 = g1 ? lf : (g2 ? cb + 3 : lf2);
                        lv  = g1 ? q3 : lv;              lf  = g1 ? cb + 3 : lf;
                    }
                    float nv, nv2; int nc, nc2;
                    wave_top2(lv, lf, lv2, lf2, nv, nc, nv2, nc2);
                    if (lane == ln) {
#pragma unroll
                        for (int jj = 0; jj < 4; ++jj) if (jj == j) {
                            rv[jj] = nv; rc[jj] = nc;
                            spv[jj] = nv2; spc[jj] = nc2;   // nc2==300 if none
                        }
                    }
                }
            }
        }
    }
}

extern "C" void kernel_launch(void* const* d_in, const int* in_sizes, int n_in,
                              void* d_out, int out_size, void* d_ws, size_t ws_size,
                              hipStream_t stream) {
    const float* soft = (const float*)d_in[0];
    float* out = (float*)d_out;
    const int n_batches = in_sizes[0] >> 16;   // elements / (256*256)

    // Static 64 KiB LDS: no runtime attribute, no silent fallback.
    greedy_perm_kernel<<<n_batches, 64, 0, stream>>>(soft, out);
}